// Round 9
// baseline (165.903 us; speedup 1.0000x reference)
//
#include <hip/hip_runtime.h>

// NCC loss (win=21) on vol [B=2, C=1, X=160, Y=192, Z=160] fp32.
// P1: products + y-filter -> Fy (fp8). R9 geometry: YSEG 12->16 (fewer init
//   re-reads: 2.67 -> 2.25 row-reads/output, FETCH ~102 -> ~93 MB) and
//   64-thread blocks (2400 blocks = 9.4/CU: tail quantization 1.28x -> 1.07x).
//   R4/R5 evidence: P1 tracks bytes at ~3.4 TB/s effective + tail factor.
// P2 k_fused_xz (R8-verbatim, <44 us): x-filter + z-filter + cc fused, H never
//   materialized. 200 producer threads own private register x-rings; 20-x
//   groups handed to 256 consumers via 19.2 KB fp8 LDS; 4 barriers/block.
// P4 sums 1536 partials. No atomics/fences (R3: same-address f64 atomic +
// device fence serialized ~31 ns/block). fp8 e4m3 intermediates; I^2/J^2
// carry x0.25 scale, cc_term unscales x4.

typedef unsigned char u8;
typedef float f2v __attribute__((ext_vector_type(2)));

#define B_   2
#define X_   160
#define Y_   192
#define Z_   160
#define WIN_ 21
#define HALF 10
#define YZ   (Y_ * Z_)                        // 30720
#define XYZ  (X_ * YZ)                        // 4915200
#define NTOT ((size_t)B_ * X_ * Y_ * Z_)      // 9830400 (elements == bytes in fp8)
#define SXN  (B_ * X_)                        // 320

#define YSEG1 16                              // P1: 12 y-segments of 16
#define NSEG1 12
#define TPB1  64                              // 1-wave blocks (tail quantization)
#define NBLK1 2400                            // 40 zg x 320 bx x 12 seg / 64

// fused kernel geometry
#define XSEG   40                             // x-extent per block (4 segs)
#define XGRP   20                             // x-group per produce/consume phase
#define LSTR   48                             // LDS line stride (dwords): 4 | 40 | 4
#define NLINES (XGRP * 5)                     // 100 LDS lines
#define TPB_F  256
#define NBLK_F (384 * 4)                      // 1536 = (B*Y) lines x 4 x-segs
#define NUNITS (XGRP * 20)                    // 400 consume units per group

__device__ __forceinline__ uint pack4_fp8(float a, float b, float c, float d)
{
    int u = 0;
    u = __builtin_amdgcn_cvt_pk_fp8_f32(a, b, u, false);
    u = __builtin_amdgcn_cvt_pk_fp8_f32(c, d, u, true);
    return (uint)u;
}

__device__ __forceinline__ float4 unpack4_fp8(uint u)
{
    f2v lo = __builtin_amdgcn_cvt_pk_f32_fp8((int)u, false);
    f2v hi = __builtin_amdgcn_cvt_pk_f32_fp8((int)u, true);
    return make_float4(lo[0], lo[1], hi[0], hi[1]);
}

__device__ __forceinline__ void upd_add(float4& W, const float4 v)
{
    W.x += v.x; W.y += v.y; W.z += v.z; W.w += v.w;
}
__device__ __forceinline__ void upd_fma(float4& W, const float4 a, const float4 b)
{
    W.x = fmaf(a.x, b.x, W.x); W.y = fmaf(a.y, b.y, W.y);
    W.z = fmaf(a.z, b.z, W.z); W.w = fmaf(a.w, b.w, W.w);
}
__device__ __forceinline__ void upd_sub2(float4& W, const float4 e, const float4 l)
{
    W.x += e.x - l.x; W.y += e.y - l.y; W.z += e.z - l.z; W.w += e.w - l.w;
}
__device__ __forceinline__ void upd_fms(float4& W, const float4 ea, const float4 eb,
                                        const float4 la, const float4 lb)
{
    W.x = fmaf(ea.x, eb.x, fmaf(-la.x, lb.x, W.x));
    W.y = fmaf(ea.y, eb.y, fmaf(-la.y, lb.y, W.y));
    W.z = fmaf(ea.z, eb.z, fmaf(-la.z, lb.z, W.z));
    W.w = fmaf(ea.w, eb.w, fmaf(-la.w, lb.w, W.w));
}

// ---------------- P1: products + y-filter, 3-mode template ----------------
#define GNONE 0
#define GLO   1
#define GHI   2

template<int MODE>
__device__ __forceinline__ void yfilt_run(int y0,
                                          const float* __restrict__ Ib,
                                          const float* __restrict__ Jb,
                                          u8* __restrict__ Fb)
{
    const float4 z4 = make_float4(0.f, 0.f, 0.f, 0.f);
    float4 W0 = z4, W1 = z4, W2 = z4, W3 = z4, W4 = z4;

    // init: window sum over raw rows [y0-10, y0+9]
#pragma unroll
    for (int k = 0; k < 20; ++k) {
        int u = y0 - 10 + k;
        float4 a, b;
        if (MODE == GLO) {                     // seg 0 only: u may be < 0
            a = (u >= 0) ? *(const float4*)(Ib + (size_t)u * Z_) : z4;
            b = (u >= 0) ? *(const float4*)(Jb + (size_t)u * Z_) : z4;
        } else {
            a = *(const float4*)(Ib + (size_t)u * Z_);
            b = *(const float4*)(Jb + (size_t)u * Z_);
        }
        upd_add(W0, a);
        upd_add(W1, b);
        upd_fma(W2, a, a);
        upd_fma(W3, b, b);
        upd_fma(W4, a, b);
    }

#pragma unroll 4
    for (int r = 0; r < YSEG1; ++r) {
        int y  = y0 + r;
        int ye = y + HALF;
        int yl = y - HALF - 1;
        float4 ea, eb, la, lb;
        if (MODE == GHI) {                     // last seg: ye may be >= Y_
            ea = (ye < Y_) ? *(const float4*)(Ib + (size_t)ye * Z_) : z4;
            eb = (ye < Y_) ? *(const float4*)(Jb + (size_t)ye * Z_) : z4;
        } else {
            ea = *(const float4*)(Ib + (size_t)ye * Z_);
            eb = *(const float4*)(Jb + (size_t)ye * Z_);
        }
        if (MODE == GLO) {                     // seg 0: yl may be < 0
            la = (yl >= 0) ? *(const float4*)(Ib + (size_t)yl * Z_) : z4;
            lb = (yl >= 0) ? *(const float4*)(Jb + (size_t)yl * Z_) : z4;
        } else {
            la = *(const float4*)(Ib + (size_t)yl * Z_);
            lb = *(const float4*)(Jb + (size_t)yl * Z_);
        }
        upd_sub2(W0, ea, la);
        upd_sub2(W1, eb, lb);
        upd_fms(W2, ea, ea, la, la);
        upd_fms(W3, eb, eb, lb, lb);
        upd_fms(W4, ea, eb, la, lb);
        size_t o = (size_t)y * Z_;
        *(uint*)(Fb + o)            = pack4_fp8(W0.x, W0.y, W0.z, W0.w);
        *(uint*)(Fb + NTOT + o)     = pack4_fp8(W1.x, W1.y, W1.z, W1.w);
        *(uint*)(Fb + 2 * NTOT + o) = pack4_fp8(W2.x * 0.25f, W2.y * 0.25f,
                                                W2.z * 0.25f, W2.w * 0.25f);
        *(uint*)(Fb + 3 * NTOT + o) = pack4_fp8(W3.x * 0.25f, W3.y * 0.25f,
                                                W3.z * 0.25f, W3.w * 0.25f);
        *(uint*)(Fb + 4 * NTOT + o) = pack4_fp8(W4.x, W4.y, W4.z, W4.w);
    }
}

// thread = (seg, bx, z4). 2400 blocks x 64 = 153600 = 40 zg x 320 bx x 12 seg.
// seg uniform per block (12800 threads per seg, 64 | 12800 -> 200 blocks/seg).
__global__ __launch_bounds__(TPB1) void k_prod_yfilt(
    const float* __restrict__ I, const float* __restrict__ J,
    u8* __restrict__ Fy)
{
    int t   = blockIdx.x * TPB1 + threadIdx.x;
    int zg  = t % 40;
    int col = t / 40;
    int bx  = col % SXN;
    int seg = col / SXN;                       // [0, 12)
    const float* Ib = I + (size_t)bx * YZ + zg * 4;
    const float* Jb = J + (size_t)bx * YZ + zg * 4;
    u8* Fb = Fy + (size_t)bx * YZ + zg * 4;
    int y0 = seg * YSEG1;

    if (seg == 0)                 yfilt_run<GLO>(y0, Ib, Jb, Fb);
    else if (seg == NSEG1 - 1)    yfilt_run<GHI>(y0, Ib, Jb, Fb);
    else                          yfilt_run<GNONE>(y0, Ib, Jb, Fb);
}

// ---------------- P2: FUSED x-filter + z-filter + cc (R8-verbatim) ----------------
__device__ __forceinline__ float cc_term(float w0, float w1, float w2, float w3,
                                         float w4, float inv_n)
{
    float cross = fmaf(-(w0 * w1), inv_n, w4);
    float Iv    = fmaf(-(w0 * w0), inv_n, w2 * 4.0f);   // unscale I2 (x0.25 in P1)
    float Jv    = fmaf(-(w1 * w1), inv_n, w3 * 4.0f);   // unscale J2
    float denom = fmaf(Iv, Jv, 1e-5f);
    return (cross * cross) * __builtin_amdgcn_rcpf(denom);
}

// z-window + cc for one (x-line, z8) unit from LDS
__device__ __forceinline__ float consume_unit(const uint* __restrict__ lds, int u,
                                              float inv_n)
{
    int xl = u / 20;
    int zg = u % 20;                           // z0 = 8*zg
    int ub = xl * 5 * LSTR + 4 + 2 * zg - 3;   // margins make all reads valid

    float s5[5][8];
#pragma unroll
    for (int c5 = 0; c5 < 5; ++c5) {
        int la = ub + c5 * LSTR;
        float f[32];                           // z span [z0-12, z0+19]
#pragma unroll
        for (int k = 0; k < 8; ++k) {
            float4 v = unpack4_fp8(lds[la + k]);
            f[4 * k + 0] = v.x; f[4 * k + 1] = v.y;
            f[4 * k + 2] = v.z; f[4 * k + 3] = v.w;
        }
        float s0 = 0.f;
#pragma unroll
        for (int i = 2; i <= 22; ++i) s0 += f[i];
        s5[c5][0] = s0;
#pragma unroll
        for (int r = 1; r < 8; ++r) { s0 += f[r + 22] - f[r + 1]; s5[c5][r] = s0; }
    }
    float a = 0.f;
#pragma unroll
    for (int r = 0; r < 8; ++r)
        a += cc_term(s5[0][r], s5[1][r], s5[2][r], s5[3][r], s5[4][r], inv_n);
    return a;
}

template<int SEG>
__device__ __forceinline__ void fused_body(const u8* __restrict__ Fy,
                                           double* __restrict__ part,
                                           int b, int y, int tid, int bid,
                                           uint* __restrict__ lds,
                                           float* __restrict__ wsum)
{
    constexpr int X0 = SEG * XSEG;
    const float inv_n = 1.0f / 9261.0f;

    // zero the z-margins of all 100 LDS lines (dwords 0..3 and 44..47)
#pragma unroll
    for (int it = 0; it < 4; ++it) {
        int i = tid + it * TPB_F;
        if (i < NLINES * 8) {
            int ln = i >> 3, m = i & 7;
            lds[ln * LSTR + (m < 4 ? m : 40 + m)] = 0u;
        }
    }

    // producers: 200 threads = (ch, z4), each with a private 21-deep x-ring
    const bool prod = (tid < 200);
    int c  = tid / 40;                         // [0,5)
    int z4 = tid % 40;
    const u8* base = Fy + (size_t)c * NTOT + (size_t)b * XYZ
                   + (size_t)y * Z_ + (size_t)z4 * 4;

    uint ring[WIN_];
    float4 W = make_float4(0.f, 0.f, 0.f, 0.f);
    if (prod) {
        // preload raw x-rows [X0-11, X0+9] (first step adds X0+10, drops X0-11)
#pragma unroll
        for (int k = 0; k < WIN_; ++k) {
            const int r = X0 - 11 + k;         // SEG>0: r >= 29, no guard
            uint v = 0u;
            if (SEG > 0 || r >= 0) v = *(const uint*)(base + (size_t)r * YZ);
            ring[k] = v;
            float4 t = unpack4_fp8(v);
            W.x += t.x; W.y += t.y; W.z += t.z; W.w += t.w;
        }
    }
    __syncthreads();                           // margins ready

    float lacc = 0.f;
#pragma unroll
    for (int g = 0; g < 2; ++g) {
        if (prod) {
#pragma unroll
            for (int s = 0; s < XGRP; ++s) {
                const int step = g * XGRP + s; // compile-time
                const int x    = X0 + step;
                const int ri   = step % WIN_;  // compile-time ring slot
                uint e = 0u;
                if (SEG < 3 || x + HALF < X_)  // static per iteration
                    e = *(const uint*)(base + (size_t)(x + HALF) * YZ);
                float4 te = unpack4_fp8(e);
                float4 tl = unpack4_fp8(ring[ri]);   // leaving raw row x-11
                W.x += te.x - tl.x; W.y += te.y - tl.y;
                W.z += te.z - tl.z; W.w += te.w - tl.w;
                ring[ri] = e;
                lds[(s * 5 + c) * LSTR + 4 + z4] = pack4_fp8(W.x, W.y, W.z, W.w);
            }
        }
        __syncthreads();                       // group's 20 x-slices ready
        lacc += consume_unit(lds, tid, inv_n);
        if (tid < NUNITS - TPB_F)              // units 256..399
            lacc += consume_unit(lds, tid + TPB_F, inv_n);
        __syncthreads();                       // before next group overwrites
    }

#pragma unroll
    for (int off = 32; off > 0; off >>= 1) lacc += __shfl_down(lacc, off);
    if ((tid & 63) == 0) wsum[tid >> 6] = lacc;
    __syncthreads();
    if (tid == 0)
        part[bid] = (double)((wsum[0] + wsum[1]) + (wsum[2] + wsum[3]));
}

// 1536 blocks x 256: block = ((b,y) line, x-seg).
__global__ __launch_bounds__(TPB_F) void k_fused_xz(const u8* __restrict__ Fy,
                                                    double* __restrict__ part)
{
    __shared__ uint  lds[NLINES * LSTR];       // 19200 B
    __shared__ float wsum[TPB_F / 64];
    int tid  = threadIdx.x;
    int bid  = blockIdx.x;
    int seg  = bid / 384;
    int line = bid % 384;
    int b = line / Y_;
    int y = line % Y_;
    switch (seg) {
        case 0:  fused_body<0>(Fy, part, b, y, tid, bid, lds, wsum); break;
        case 1:  fused_body<1>(Fy, part, b, y, tid, bid, lds, wsum); break;
        case 2:  fused_body<2>(Fy, part, b, y, tid, bid, lds, wsum); break;
        default: fused_body<3>(Fy, part, b, y, tid, bid, lds, wsum); break;
    }
}

// ---------------- P4: sum 1536 partials + finalize ----------------
__global__ __launch_bounds__(256) void k_final4(const double* __restrict__ part,
                                                float* __restrict__ out)
{
    int tid = threadIdx.x;
    double s = 0.0;
#pragma unroll
    for (int k = 0; k < NBLK_F / 256; ++k)     // 6 each
        s += part[tid + 256 * k];
#pragma unroll
    for (int off = 32; off > 0; off >>= 1) s += __shfl_down(s, off);
    __shared__ double wsum[4];
    if ((tid & 63) == 0) wsum[tid >> 6] = s;
    __syncthreads();
    if (tid == 0) {
        double tot = (wsum[0] + wsum[1]) + (wsum[2] + wsum[3]);
        out[0] = 1.0f - (float)(tot / 9830400.0);
    }
}

extern "C" void kernel_launch(void* const* d_in, const int* in_sizes, int n_in,
                              void* d_out, int out_size, void* d_ws, size_t ws_size,
                              hipStream_t stream)
{
    const float* I = (const float*)d_in[0];
    const float* J = (const float*)d_in[1];
    float* out = (float*)d_out;

    char* ws = (char*)d_ws;
    double* part = (double*)ws;                // 1536 doubles
    u8* Fy = (u8*)(ws + 32768);                // 5 x 9.83 MB = 49.2 MB (fp8)

    k_prod_yfilt<<<dim3(NBLK1), TPB1, 0, stream>>>(I, J, Fy);
    k_fused_xz<<<dim3(NBLK_F), TPB_F, 0, stream>>>(Fy, part);
    k_final4<<<dim3(1), 256, 0, stream>>>(part, out);
}

// Round 11
// 165.273 us; speedup vs baseline: 1.0038x; 1.0038x over previous
//
#include <hip/hip_runtime.h>

// NCC loss (win=21) on vol [B=2, C=1, X=160, Y=192, Z=160] fp32.
// P1: products + y-filter -> Fy (fp8). R8-exact geometry (YSEG 12, 800x256):
//   measured 45 us, pinned at bytes/3.4 TB/s (R1/R4/R5/R9 evidence).
// P2 k_fused_xz: x-filter + z-filter + cc fused (H never materialized).
//   R10/R11: TPB 256->320 (5 waves) + disjoint produce/double-consume sets --
//   producers are tids 0..199, the 80 second consume-units go to tids
//   240..319 (previously both piled on waves 0-2 while wave 3 idled at all
//   5 barriers). 1536 blocks = 6/CU x 5 waves = 30 waves/CU.
//   (R10 bench was an infra failure -- container died; this is a resubmit.)
// P4 sums 1536 partials. No atomics/fences (R3: ~31 ns/block serialization).
// fp8 e4m3 intermediates; I^2/J^2 carry x0.25 scale, cc_term unscales x4.

typedef unsigned char u8;
typedef float f2v __attribute__((ext_vector_type(2)));

#define B_   2
#define X_   160
#define Y_   192
#define Z_   160
#define WIN_ 21
#define HALF 10
#define YZ   (Y_ * Z_)                        // 30720
#define XYZ  (X_ * YZ)                        // 4915200
#define NTOT ((size_t)B_ * X_ * Y_ * Z_)      // 9830400 (elements == bytes in fp8)
#define SXN  (B_ * X_)                        // 320

#define YSEG1 12                              // P1: 16 y-segments of 12 (R4/R8 best)

// fused kernel geometry
#define XSEG   40                             // x-extent per block (4 segs)
#define XGRP   20                             // x-group per produce/consume phase
#define LSTR   48                             // LDS line stride (dwords): 4 | 40 | 4
#define NLINES (XGRP * 5)                     // 100 LDS lines
#define TPB_F  320                            // 5 waves
#define NBLK_F (384 * 4)                      // 1536 = (B*Y) lines x 4 x-segs
#define NUNITS (XGRP * 20)                    // 400 consume units per group

__device__ __forceinline__ uint pack4_fp8(float a, float b, float c, float d)
{
    int u = 0;
    u = __builtin_amdgcn_cvt_pk_fp8_f32(a, b, u, false);
    u = __builtin_amdgcn_cvt_pk_fp8_f32(c, d, u, true);
    return (uint)u;
}

__device__ __forceinline__ float4 unpack4_fp8(uint u)
{
    f2v lo = __builtin_amdgcn_cvt_pk_f32_fp8((int)u, false);
    f2v hi = __builtin_amdgcn_cvt_pk_f32_fp8((int)u, true);
    return make_float4(lo[0], lo[1], hi[0], hi[1]);
}

__device__ __forceinline__ void upd_add(float4& W, const float4 v)
{
    W.x += v.x; W.y += v.y; W.z += v.z; W.w += v.w;
}
__device__ __forceinline__ void upd_fma(float4& W, const float4 a, const float4 b)
{
    W.x = fmaf(a.x, b.x, W.x); W.y = fmaf(a.y, b.y, W.y);
    W.z = fmaf(a.z, b.z, W.z); W.w = fmaf(a.w, b.w, W.w);
}
__device__ __forceinline__ void upd_sub2(float4& W, const float4 e, const float4 l)
{
    W.x += e.x - l.x; W.y += e.y - l.y; W.z += e.z - l.z; W.w += e.w - l.w;
}
__device__ __forceinline__ void upd_fms(float4& W, const float4 ea, const float4 eb,
                                        const float4 la, const float4 lb)
{
    W.x = fmaf(ea.x, eb.x, fmaf(-la.x, lb.x, W.x));
    W.y = fmaf(ea.y, eb.y, fmaf(-la.y, lb.y, W.y));
    W.z = fmaf(ea.z, eb.z, fmaf(-la.z, lb.z, W.z));
    W.w = fmaf(ea.w, eb.w, fmaf(-la.w, lb.w, W.w));
}

// ---------------- P1: products + y-filter (R8-verbatim, measured 45 us) -------------
#define GNONE 0
#define GLO   1
#define GHI   2

template<int MODE>
__device__ __forceinline__ void yfilt_run(int y0,
                                          const float* __restrict__ Ib,
                                          const float* __restrict__ Jb,
                                          u8* __restrict__ Fb)
{
    const float4 z4 = make_float4(0.f, 0.f, 0.f, 0.f);
    float4 W0 = z4, W1 = z4, W2 = z4, W3 = z4, W4 = z4;

    // init: window sum over raw rows [y0-10, y0+9]
#pragma unroll
    for (int k = 0; k < 20; ++k) {
        int u = y0 - 10 + k;
        float4 a, b;
        if (MODE == GLO) {                     // seg 0 only: u may be < 0
            a = (u >= 0) ? *(const float4*)(Ib + (size_t)u * Z_) : z4;
            b = (u >= 0) ? *(const float4*)(Jb + (size_t)u * Z_) : z4;
        } else {
            a = *(const float4*)(Ib + (size_t)u * Z_);
            b = *(const float4*)(Jb + (size_t)u * Z_);
        }
        upd_add(W0, a);
        upd_add(W1, b);
        upd_fma(W2, a, a);
        upd_fma(W3, b, b);
        upd_fma(W4, a, b);
    }

#pragma unroll
    for (int r = 0; r < YSEG1; ++r) {
        int y  = y0 + r;
        int ye = y + HALF;
        int yl = y - HALF - 1;
        float4 ea, eb, la, lb;
        if (MODE == GHI) {                     // seg 15 only: ye may be >= Y_
            ea = (ye < Y_) ? *(const float4*)(Ib + (size_t)ye * Z_) : z4;
            eb = (ye < Y_) ? *(const float4*)(Jb + (size_t)ye * Z_) : z4;
        } else {
            ea = *(const float4*)(Ib + (size_t)ye * Z_);
            eb = *(const float4*)(Jb + (size_t)ye * Z_);
        }
        if (MODE == GLO) {                     // seg 0 only: yl may be < 0
            la = (yl >= 0) ? *(const float4*)(Ib + (size_t)yl * Z_) : z4;
            lb = (yl >= 0) ? *(const float4*)(Jb + (size_t)yl * Z_) : z4;
        } else {
            la = *(const float4*)(Ib + (size_t)yl * Z_);
            lb = *(const float4*)(Jb + (size_t)yl * Z_);
        }
        upd_sub2(W0, ea, la);
        upd_sub2(W1, eb, lb);
        upd_fms(W2, ea, ea, la, la);
        upd_fms(W3, eb, eb, lb, lb);
        upd_fms(W4, ea, eb, la, lb);
        size_t o = (size_t)y * Z_;
        *(uint*)(Fb + o)            = pack4_fp8(W0.x, W0.y, W0.z, W0.w);
        *(uint*)(Fb + NTOT + o)     = pack4_fp8(W1.x, W1.y, W1.z, W1.w);
        *(uint*)(Fb + 2 * NTOT + o) = pack4_fp8(W2.x * 0.25f, W2.y * 0.25f,
                                                W2.z * 0.25f, W2.w * 0.25f);
        *(uint*)(Fb + 3 * NTOT + o) = pack4_fp8(W3.x * 0.25f, W3.y * 0.25f,
                                                W3.z * 0.25f, W3.w * 0.25f);
        *(uint*)(Fb + 4 * NTOT + o) = pack4_fp8(W4.x, W4.y, W4.z, W4.w);
    }
}

// thread = (seg, bx, z4). 800 blocks x 256 = 204800 = 40 z4 x 320 bx x 16 seg.
__global__ __launch_bounds__(256) void k_prod_yfilt(
    const float* __restrict__ I, const float* __restrict__ J,
    u8* __restrict__ Fy)
{
    int t   = blockIdx.x * 256 + threadIdx.x;
    int zg  = t % 40;
    int col = t / 40;
    int bx  = col % SXN;
    int seg = col / SXN;                       // [0, 16)
    const float* Ib = I + (size_t)bx * YZ + zg * 4;
    const float* Jb = J + (size_t)bx * YZ + zg * 4;
    u8* Fb = Fy + (size_t)bx * YZ + zg * 4;
    int y0 = seg * YSEG1;

    if (seg == 0)            yfilt_run<GLO>(y0, Ib, Jb, Fb);
    else if (seg == 15)      yfilt_run<GHI>(y0, Ib, Jb, Fb);
    else                     yfilt_run<GNONE>(y0, Ib, Jb, Fb);
}

// ---------------- P2: FUSED x-filter + z-filter + cc ----------------
__device__ __forceinline__ float cc_term(float w0, float w1, float w2, float w3,
                                         float w4, float inv_n)
{
    float cross = fmaf(-(w0 * w1), inv_n, w4);
    float Iv    = fmaf(-(w0 * w0), inv_n, w2 * 4.0f);   // unscale I2 (x0.25 in P1)
    float Jv    = fmaf(-(w1 * w1), inv_n, w3 * 4.0f);   // unscale J2
    float denom = fmaf(Iv, Jv, 1e-5f);
    return (cross * cross) * __builtin_amdgcn_rcpf(denom);
}

// z-window + cc for one (x-line, z8) unit from LDS (R8 correctness-proven)
__device__ __forceinline__ float consume_unit(const uint* __restrict__ lds, int u,
                                              float inv_n)
{
    int xl = u / 20;
    int zg = u % 20;                           // z0 = 8*zg
    int ub = xl * 5 * LSTR + 4 + 2 * zg - 3;   // margins make all reads valid

    float s5[5][8];
#pragma unroll
    for (int c5 = 0; c5 < 5; ++c5) {
        int la = ub + c5 * LSTR;
        float f[32];                           // z span [z0-12, z0+19]
#pragma unroll
        for (int k = 0; k < 8; ++k) {
            float4 v = unpack4_fp8(lds[la + k]);
            f[4 * k + 0] = v.x; f[4 * k + 1] = v.y;
            f[4 * k + 2] = v.z; f[4 * k + 3] = v.w;
        }
        float s0 = 0.f;
#pragma unroll
        for (int i = 2; i <= 22; ++i) s0 += f[i];
        s5[c5][0] = s0;
#pragma unroll
        for (int r = 1; r < 8; ++r) { s0 += f[r + 22] - f[r + 1]; s5[c5][r] = s0; }
    }
    float a = 0.f;
#pragma unroll
    for (int r = 0; r < 8; ++r)
        a += cc_term(s5[0][r], s5[1][r], s5[2][r], s5[3][r], s5[4][r], inv_n);
    return a;
}

template<int SEG>
__device__ __forceinline__ void fused_body(const u8* __restrict__ Fy,
                                           double* __restrict__ part,
                                           int b, int y, int tid, int bid,
                                           uint* __restrict__ lds,
                                           float* __restrict__ wsum)
{
    constexpr int X0 = SEG * XSEG;
    const float inv_n = 1.0f / 9261.0f;

    // zero the z-margins of all 100 LDS lines (dwords 0..3 and 44..47)
#pragma unroll
    for (int it = 0; it < 3; ++it) {
        int i = tid + it * TPB_F;
        if (i < NLINES * 8) {
            int ln = i >> 3, m = i & 7;
            lds[ln * LSTR + (m < 4 ? m : 40 + m)] = 0u;
        }
    }

    // producers: tids 0..199 = (ch, z4), each with a private 21-deep x-ring
    const bool prod = (tid < 200);
    int c  = tid / 40;                         // [0,5)
    int z4 = tid % 40;
    const u8* base = Fy + (size_t)c * NTOT + (size_t)b * XYZ
                   + (size_t)y * Z_ + (size_t)z4 * 4;

    uint ring[WIN_];
    float4 W = make_float4(0.f, 0.f, 0.f, 0.f);
    if (prod) {
        // preload raw x-rows [X0-11, X0+9] (first step adds X0+10, drops X0-11)
#pragma unroll
        for (int k = 0; k < WIN_; ++k) {
            const int r = X0 - 11 + k;         // SEG>0: r >= 29, no guard
            uint v = 0u;
            if (SEG > 0 || r >= 0) v = *(const uint*)(base + (size_t)r * YZ);
            ring[k] = v;
            float4 t = unpack4_fp8(v);
            W.x += t.x; W.y += t.y; W.z += t.z; W.w += t.w;
        }
    }
    __syncthreads();                           // margins ready

    float lacc = 0.f;
#pragma unroll
    for (int g = 0; g < 2; ++g) {
        if (prod) {
#pragma unroll
            for (int s = 0; s < XGRP; ++s) {
                const int step = g * XGRP + s; // compile-time
                const int x    = X0 + step;
                const int ri   = step % WIN_;  // compile-time ring slot
                uint e = 0u;
                if (SEG < 3 || x + HALF < X_)  // static per iteration
                    e = *(const uint*)(base + (size_t)(x + HALF) * YZ);
                float4 te = unpack4_fp8(e);
                float4 tl = unpack4_fp8(ring[ri]);   // leaving raw row x-11
                W.x += te.x - tl.x; W.y += te.y - tl.y;
                W.z += te.z - tl.z; W.w += te.w - tl.w;
                ring[ri] = e;
                lds[(s * 5 + c) * LSTR + 4 + z4] = pack4_fp8(W.x, W.y, W.z, W.w);
            }
        }
        __syncthreads();                       // group's 20 x-slices ready
        // unit tid for everyone; the 80 extra units go to NON-producer tids
        // 240..319 (disjoint from producers -> waves balance across barriers)
        lacc += consume_unit(lds, tid, inv_n);
        if (tid >= TPB_F - (NUNITS - TPB_F))   // tids 240..319 -> units 320..399
            lacc += consume_unit(lds, tid + (NUNITS - TPB_F), inv_n);
        __syncthreads();                       // before next group overwrites
    }

#pragma unroll
    for (int off = 32; off > 0; off >>= 1) lacc += __shfl_down(lacc, off);
    if ((tid & 63) == 0) wsum[tid >> 6] = lacc;
    __syncthreads();
    if (tid == 0) {
        float sm = 0.f;
#pragma unroll
        for (int w = 0; w < TPB_F / 64; ++w) sm += wsum[w];
        part[bid] = (double)sm;
    }
}

// 1536 blocks x 320: block = ((b,y) line, x-seg).
__global__ __launch_bounds__(TPB_F) void k_fused_xz(const u8* __restrict__ Fy,
                                                    double* __restrict__ part)
{
    __shared__ uint  lds[NLINES * LSTR];       // 19200 B
    __shared__ float wsum[TPB_F / 64];
    int tid  = threadIdx.x;
    int bid  = blockIdx.x;
    int seg  = bid / 384;
    int line = bid % 384;
    int b = line / Y_;
    int y = line % Y_;
    switch (seg) {
        case 0:  fused_body<0>(Fy, part, b, y, tid, bid, lds, wsum); break;
        case 1:  fused_body<1>(Fy, part, b, y, tid, bid, lds, wsum); break;
        case 2:  fused_body<2>(Fy, part, b, y, tid, bid, lds, wsum); break;
        default: fused_body<3>(Fy, part, b, y, tid, bid, lds, wsum); break;
    }
}

// ---------------- P4: sum 1536 partials + finalize ----------------
__global__ __launch_bounds__(256) void k_final4(const double* __restrict__ part,
                                                float* __restrict__ out)
{
    int tid = threadIdx.x;
    double s = 0.0;
#pragma unroll
    for (int k = 0; k < NBLK_F / 256; ++k)     // 6 each
        s += part[tid + 256 * k];
#pragma unroll
    for (int off = 32; off > 0; off >>= 1) s += __shfl_down(s, off);
    __shared__ double wsum[4];
    if ((tid & 63) == 0) wsum[tid >> 6] = s;
    __syncthreads();
    if (tid == 0) {
        double tot = (wsum[0] + wsum[1]) + (wsum[2] + wsum[3]);
        out[0] = 1.0f - (float)(tot / 9830400.0);
    }
}

extern "C" void kernel_launch(void* const* d_in, const int* in_sizes, int n_in,
                              void* d_out, int out_size, void* d_ws, size_t ws_size,
                              hipStream_t stream)
{
    const float* I = (const float*)d_in[0];
    const float* J = (const float*)d_in[1];
    float* out = (float*)d_out;

    char* ws = (char*)d_ws;
    double* part = (double*)ws;                // 1536 doubles
    u8* Fy = (u8*)(ws + 32768);                // 5 x 9.83 MB = 49.2 MB (fp8)

    k_prod_yfilt<<<dim3(800), 256, 0, stream>>>(I, J, Fy);
    k_fused_xz<<<dim3(NBLK_F), TPB_F, 0, stream>>>(Fy, part);
    k_final4<<<dim3(1), 256, 0, stream>>>(part, out);
}

// Round 12
// 155.952 us; speedup vs baseline: 1.0638x; 1.0598x over previous
//
#include <hip/hip_runtime.h>

// NCC loss (win=21) on vol [B=2, C=1, X=160, Y=192, Z=160] fp32.
// P1: products + y-filter -> Fy (fp8). R8-exact geometry (YSEG 12, 800x256):
//   measured 45 us, pinned at bytes/3.4 TB/s (R1/R4/R5/R9 evidence).
// P2 k_fused_xz: x-filter + z-filter + cc fused (H never materialized).
//   R12: back to R8-exact structure (TPB 256 -- R11's TPB 320 regressed) with
//   ONE change: LSTR 48 -> 49. With 48, every consume-side LDS address was
//   even mod 32 (240, 48, 2*zg all even) -> all 64 lanes in 16 banks -> 4-way
//   conflict on EVERY read (measured 2.93M conflict cycles). Odd stride mixes
//   parity across c5/xl -> conflicts collapse.
// P4 sums 1536 partials. No atomics/fences (R3: ~31 ns/block serialization).
// fp8 e4m3 intermediates; I^2/J^2 carry x0.25 scale, cc_term unscales x4.

typedef unsigned char u8;
typedef float f2v __attribute__((ext_vector_type(2)));

#define B_   2
#define X_   160
#define Y_   192
#define Z_   160
#define WIN_ 21
#define HALF 10
#define YZ   (Y_ * Z_)                        // 30720
#define XYZ  (X_ * YZ)                        // 4915200
#define NTOT ((size_t)B_ * X_ * Y_ * Z_)      // 9830400 (elements == bytes in fp8)
#define SXN  (B_ * X_)                        // 320

#define YSEG1 12                              // P1: 16 y-segments of 12 (R4/R8 best)

// fused kernel geometry
#define XSEG   40                             // x-extent per block (4 segs)
#define XGRP   20                             // x-group per produce/consume phase
#define LSTR   49                             // LDS line stride (dwords, ODD): 4|40|4|1
#define NLINES (XGRP * 5)                     // 100 LDS lines
#define TPB_F  256
#define NBLK_F (384 * 4)                      // 1536 = (B*Y) lines x 4 x-segs
#define NUNITS (XGRP * 20)                    // 400 consume units per group

__device__ __forceinline__ uint pack4_fp8(float a, float b, float c, float d)
{
    int u = 0;
    u = __builtin_amdgcn_cvt_pk_fp8_f32(a, b, u, false);
    u = __builtin_amdgcn_cvt_pk_fp8_f32(c, d, u, true);
    return (uint)u;
}

__device__ __forceinline__ float4 unpack4_fp8(uint u)
{
    f2v lo = __builtin_amdgcn_cvt_pk_f32_fp8((int)u, false);
    f2v hi = __builtin_amdgcn_cvt_pk_f32_fp8((int)u, true);
    return make_float4(lo[0], lo[1], hi[0], hi[1]);
}

__device__ __forceinline__ void upd_add(float4& W, const float4 v)
{
    W.x += v.x; W.y += v.y; W.z += v.z; W.w += v.w;
}
__device__ __forceinline__ void upd_fma(float4& W, const float4 a, const float4 b)
{
    W.x = fmaf(a.x, b.x, W.x); W.y = fmaf(a.y, b.y, W.y);
    W.z = fmaf(a.z, b.z, W.z); W.w = fmaf(a.w, b.w, W.w);
}
__device__ __forceinline__ void upd_sub2(float4& W, const float4 e, const float4 l)
{
    W.x += e.x - l.x; W.y += e.y - l.y; W.z += e.z - l.z; W.w += e.w - l.w;
}
__device__ __forceinline__ void upd_fms(float4& W, const float4 ea, const float4 eb,
                                        const float4 la, const float4 lb)
{
    W.x = fmaf(ea.x, eb.x, fmaf(-la.x, lb.x, W.x));
    W.y = fmaf(ea.y, eb.y, fmaf(-la.y, lb.y, W.y));
    W.z = fmaf(ea.z, eb.z, fmaf(-la.z, lb.z, W.z));
    W.w = fmaf(ea.w, eb.w, fmaf(-la.w, lb.w, W.w));
}

// ---------------- P1: products + y-filter (R8-verbatim, measured 45 us) -------------
#define GNONE 0
#define GLO   1
#define GHI   2

template<int MODE>
__device__ __forceinline__ void yfilt_run(int y0,
                                          const float* __restrict__ Ib,
                                          const float* __restrict__ Jb,
                                          u8* __restrict__ Fb)
{
    const float4 z4 = make_float4(0.f, 0.f, 0.f, 0.f);
    float4 W0 = z4, W1 = z4, W2 = z4, W3 = z4, W4 = z4;

    // init: window sum over raw rows [y0-10, y0+9]
#pragma unroll
    for (int k = 0; k < 20; ++k) {
        int u = y0 - 10 + k;
        float4 a, b;
        if (MODE == GLO) {                     // seg 0 only: u may be < 0
            a = (u >= 0) ? *(const float4*)(Ib + (size_t)u * Z_) : z4;
            b = (u >= 0) ? *(const float4*)(Jb + (size_t)u * Z_) : z4;
        } else {
            a = *(const float4*)(Ib + (size_t)u * Z_);
            b = *(const float4*)(Jb + (size_t)u * Z_);
        }
        upd_add(W0, a);
        upd_add(W1, b);
        upd_fma(W2, a, a);
        upd_fma(W3, b, b);
        upd_fma(W4, a, b);
    }

#pragma unroll
    for (int r = 0; r < YSEG1; ++r) {
        int y  = y0 + r;
        int ye = y + HALF;
        int yl = y - HALF - 1;
        float4 ea, eb, la, lb;
        if (MODE == GHI) {                     // seg 15 only: ye may be >= Y_
            ea = (ye < Y_) ? *(const float4*)(Ib + (size_t)ye * Z_) : z4;
            eb = (ye < Y_) ? *(const float4*)(Jb + (size_t)ye * Z_) : z4;
        } else {
            ea = *(const float4*)(Ib + (size_t)ye * Z_);
            eb = *(const float4*)(Jb + (size_t)ye * Z_);
        }
        if (MODE == GLO) {                     // seg 0 only: yl may be < 0
            la = (yl >= 0) ? *(const float4*)(Ib + (size_t)yl * Z_) : z4;
            lb = (yl >= 0) ? *(const float4*)(Jb + (size_t)yl * Z_) : z4;
        } else {
            la = *(const float4*)(Ib + (size_t)yl * Z_);
            lb = *(const float4*)(Jb + (size_t)yl * Z_);
        }
        upd_sub2(W0, ea, la);
        upd_sub2(W1, eb, lb);
        upd_fms(W2, ea, ea, la, la);
        upd_fms(W3, eb, eb, lb, lb);
        upd_fms(W4, ea, eb, la, lb);
        size_t o = (size_t)y * Z_;
        *(uint*)(Fb + o)            = pack4_fp8(W0.x, W0.y, W0.z, W0.w);
        *(uint*)(Fb + NTOT + o)     = pack4_fp8(W1.x, W1.y, W1.z, W1.w);
        *(uint*)(Fb + 2 * NTOT + o) = pack4_fp8(W2.x * 0.25f, W2.y * 0.25f,
                                                W2.z * 0.25f, W2.w * 0.25f);
        *(uint*)(Fb + 3 * NTOT + o) = pack4_fp8(W3.x * 0.25f, W3.y * 0.25f,
                                                W3.z * 0.25f, W3.w * 0.25f);
        *(uint*)(Fb + 4 * NTOT + o) = pack4_fp8(W4.x, W4.y, W4.z, W4.w);
    }
}

// thread = (seg, bx, z4). 800 blocks x 256 = 204800 = 40 z4 x 320 bx x 16 seg.
__global__ __launch_bounds__(256) void k_prod_yfilt(
    const float* __restrict__ I, const float* __restrict__ J,
    u8* __restrict__ Fy)
{
    int t   = blockIdx.x * 256 + threadIdx.x;
    int zg  = t % 40;
    int col = t / 40;
    int bx  = col % SXN;
    int seg = col / SXN;                       // [0, 16)
    const float* Ib = I + (size_t)bx * YZ + zg * 4;
    const float* Jb = J + (size_t)bx * YZ + zg * 4;
    u8* Fb = Fy + (size_t)bx * YZ + zg * 4;
    int y0 = seg * YSEG1;

    if (seg == 0)            yfilt_run<GLO>(y0, Ib, Jb, Fb);
    else if (seg == 15)      yfilt_run<GHI>(y0, Ib, Jb, Fb);
    else                     yfilt_run<GNONE>(y0, Ib, Jb, Fb);
}

// ---------------- P2: FUSED x-filter + z-filter + cc (R8 structure) ----------------
__device__ __forceinline__ float cc_term(float w0, float w1, float w2, float w3,
                                         float w4, float inv_n)
{
    float cross = fmaf(-(w0 * w1), inv_n, w4);
    float Iv    = fmaf(-(w0 * w0), inv_n, w2 * 4.0f);   // unscale I2 (x0.25 in P1)
    float Jv    = fmaf(-(w1 * w1), inv_n, w3 * 4.0f);   // unscale J2
    float denom = fmaf(Iv, Jv, 1e-5f);
    return (cross * cross) * __builtin_amdgcn_rcpf(denom);
}

// z-window + cc for one (x-line, z8) unit from LDS
__device__ __forceinline__ float consume_unit(const uint* __restrict__ lds, int u,
                                              float inv_n)
{
    int xl = u / 20;
    int zg = u % 20;                           // z0 = 8*zg
    int ub = xl * 5 * LSTR + 4 + 2 * zg - 3;   // margins make all reads valid

    float s5[5][8];
#pragma unroll
    for (int c5 = 0; c5 < 5; ++c5) {
        int la = ub + c5 * LSTR;
        float f[32];                           // z span [z0-12, z0+19]
#pragma unroll
        for (int k = 0; k < 8; ++k) {
            float4 v = unpack4_fp8(lds[la + k]);
            f[4 * k + 0] = v.x; f[4 * k + 1] = v.y;
            f[4 * k + 2] = v.z; f[4 * k + 3] = v.w;
        }
        float s0 = 0.f;
#pragma unroll
        for (int i = 2; i <= 22; ++i) s0 += f[i];
        s5[c5][0] = s0;
#pragma unroll
        for (int r = 1; r < 8; ++r) { s0 += f[r + 22] - f[r + 1]; s5[c5][r] = s0; }
    }
    float a = 0.f;
#pragma unroll
    for (int r = 0; r < 8; ++r)
        a += cc_term(s5[0][r], s5[1][r], s5[2][r], s5[3][r], s5[4][r], inv_n);
    return a;
}

template<int SEG>
__device__ __forceinline__ void fused_body(const u8* __restrict__ Fy,
                                           double* __restrict__ part,
                                           int b, int y, int tid, int bid,
                                           uint* __restrict__ lds,
                                           float* __restrict__ wsum)
{
    constexpr int X0 = SEG * XSEG;
    const float inv_n = 1.0f / 9261.0f;

    // zero the z-margins of all 100 LDS lines (dwords 0..3 and 44..47)
#pragma unroll
    for (int it = 0; it < 4; ++it) {
        int i = tid + it * TPB_F;
        if (i < NLINES * 8) {
            int ln = i >> 3, m = i & 7;
            lds[ln * LSTR + (m < 4 ? m : 40 + m)] = 0u;
        }
    }

    // producers: 200 threads = (ch, z4), each with a private 21-deep x-ring
    const bool prod = (tid < 200);
    int c  = tid / 40;                         // [0,5)
    int z4 = tid % 40;
    const u8* base = Fy + (size_t)c * NTOT + (size_t)b * XYZ
                   + (size_t)y * Z_ + (size_t)z4 * 4;

    uint ring[WIN_];
    float4 W = make_float4(0.f, 0.f, 0.f, 0.f);
    if (prod) {
        // preload raw x-rows [X0-11, X0+9] (first step adds X0+10, drops X0-11)
#pragma unroll
        for (int k = 0; k < WIN_; ++k) {
            const int r = X0 - 11 + k;         // SEG>0: r >= 29, no guard
            uint v = 0u;
            if (SEG > 0 || r >= 0) v = *(const uint*)(base + (size_t)r * YZ);
            ring[k] = v;
            float4 t = unpack4_fp8(v);
            W.x += t.x; W.y += t.y; W.z += t.z; W.w += t.w;
        }
    }
    __syncthreads();                           // margins ready

    float lacc = 0.f;
#pragma unroll
    for (int g = 0; g < 2; ++g) {
        if (prod) {
#pragma unroll
            for (int s = 0; s < XGRP; ++s) {
                const int step = g * XGRP + s; // compile-time
                const int x    = X0 + step;
                const int ri   = step % WIN_;  // compile-time ring slot
                uint e = 0u;
                if (SEG < 3 || x + HALF < X_)  // static per iteration
                    e = *(const uint*)(base + (size_t)(x + HALF) * YZ);
                float4 te = unpack4_fp8(e);
                float4 tl = unpack4_fp8(ring[ri]);   // leaving raw row x-11
                W.x += te.x - tl.x; W.y += te.y - tl.y;
                W.z += te.z - tl.z; W.w += te.w - tl.w;
                ring[ri] = e;
                lds[(s * 5 + c) * LSTR + 4 + z4] = pack4_fp8(W.x, W.y, W.z, W.w);
            }
        }
        __syncthreads();                       // group's 20 x-slices ready
        lacc += consume_unit(lds, tid, inv_n);
        if (tid < NUNITS - TPB_F)              // units 256..399
            lacc += consume_unit(lds, tid + TPB_F, inv_n);
        __syncthreads();                       // before next group overwrites
    }

#pragma unroll
    for (int off = 32; off > 0; off >>= 1) lacc += __shfl_down(lacc, off);
    if ((tid & 63) == 0) wsum[tid >> 6] = lacc;
    __syncthreads();
    if (tid == 0)
        part[bid] = (double)((wsum[0] + wsum[1]) + (wsum[2] + wsum[3]));
}

// 1536 blocks x 256: block = ((b,y) line, x-seg).
__global__ __launch_bounds__(TPB_F) void k_fused_xz(const u8* __restrict__ Fy,
                                                    double* __restrict__ part)
{
    __shared__ uint  lds[NLINES * LSTR];       // 19600 B
    __shared__ float wsum[TPB_F / 64];
    int tid  = threadIdx.x;
    int bid  = blockIdx.x;
    int seg  = bid / 384;
    int line = bid % 384;
    int b = line / Y_;
    int y = line % Y_;
    switch (seg) {
        case 0:  fused_body<0>(Fy, part, b, y, tid, bid, lds, wsum); break;
        case 1:  fused_body<1>(Fy, part, b, y, tid, bid, lds, wsum); break;
        case 2:  fused_body<2>(Fy, part, b, y, tid, bid, lds, wsum); break;
        default: fused_body<3>(Fy, part, b, y, tid, bid, lds, wsum); break;
    }
}

// ---------------- P4: sum 1536 partials + finalize ----------------
__global__ __launch_bounds__(256) void k_final4(const double* __restrict__ part,
                                                float* __restrict__ out)
{
    int tid = threadIdx.x;
    double s = 0.0;
#pragma unroll
    for (int k = 0; k < NBLK_F / 256; ++k)     // 6 each
        s += part[tid + 256 * k];
#pragma unroll
    for (int off = 32; off > 0; off >>= 1) s += __shfl_down(s, off);
    __shared__ double wsum[4];
    if ((tid & 63) == 0) wsum[tid >> 6] = s;
    __syncthreads();
    if (tid == 0) {
        double tot = (wsum[0] + wsum[1]) + (wsum[2] + wsum[3]);
        out[0] = 1.0f - (float)(tot / 9830400.0);
    }
}

extern "C" void kernel_launch(void* const* d_in, const int* in_sizes, int n_in,
                              void* d_out, int out_size, void* d_ws, size_t ws_size,
                              hipStream_t stream)
{
    const float* I = (const float*)d_in[0];
    const float* J = (const float*)d_in[1];
    float* out = (float*)d_out;

    char* ws = (char*)d_ws;
    double* part = (double*)ws;                // 1536 doubles
    u8* Fy = (u8*)(ws + 32768);                // 5 x 9.83 MB = 49.2 MB (fp8)

    k_prod_yfilt<<<dim3(800), 256, 0, stream>>>(I, J, Fy);
    k_fused_xz<<<dim3(NBLK_F), TPB_F, 0, stream>>>(Fy, part);
    k_final4<<<dim3(1), 256, 0, stream>>>(part, out);
}

// Round 13
// 155.493 us; speedup vs baseline: 1.0670x; 1.0030x over previous
//
#include <hip/hip_runtime.h>

// NCC loss (win=21) on vol [B=2, C=1, X=160, Y=192, Z=160] fp32.
// P1: products + y-filter -> Fy (fp8). R8-exact geometry (YSEG 12, 800x256):
//   measured ~46 us, pinned at bytes/3.4 TB/s across 6 variants -- at floor.
// P2 k_fused_xz: x-filter + z-filter + cc fused (H never materialized).
//   R13: latency-hiding restructure -- (a) margin-zero and produce-g0 write
//   disjoint LDS, so they share ONE barrier (5 -> 4 barriers); (b) g1's 20
//   enter-row loads are prefetched into registers right after that barrier
//   and consumed-g0's ~2000 VALU cycles hide their latency (previously the
//   pre-produce-g1 barrier's vmcnt(0) drain exposed them fully).
//   LSTR 49 (R12: odd stride kills the all-even-parity 4-way bank conflict).
// P4 sums 1536 partials. No atomics/fences (R3: ~31 ns/block serialization).
// fp8 e4m3 intermediates; I^2/J^2 carry x0.25 scale, cc_term unscales x4.

typedef unsigned char u8;
typedef float f2v __attribute__((ext_vector_type(2)));

#define B_   2
#define X_   160
#define Y_   192
#define Z_   160
#define WIN_ 21
#define HALF 10
#define YZ   (Y_ * Z_)                        // 30720
#define XYZ  (X_ * YZ)                        // 4915200
#define NTOT ((size_t)B_ * X_ * Y_ * Z_)      // 9830400 (elements == bytes in fp8)
#define SXN  (B_ * X_)                        // 320

#define YSEG1 12                              // P1: 16 y-segments of 12 (R4/R8 best)

// fused kernel geometry
#define XSEG   40                             // x-extent per block (4 segs)
#define XGRP   20                             // x-group per produce/consume phase
#define LSTR   49                             // LDS line stride (dwords, ODD): 4|40|4|1
#define NLINES (XGRP * 5)                     // 100 LDS lines
#define TPB_F  256
#define NBLK_F (384 * 4)                      // 1536 = (B*Y) lines x 4 x-segs
#define NUNITS (XGRP * 20)                    // 400 consume units per group

__device__ __forceinline__ uint pack4_fp8(float a, float b, float c, float d)
{
    int u = 0;
    u = __builtin_amdgcn_cvt_pk_fp8_f32(a, b, u, false);
    u = __builtin_amdgcn_cvt_pk_fp8_f32(c, d, u, true);
    return (uint)u;
}

__device__ __forceinline__ float4 unpack4_fp8(uint u)
{
    f2v lo = __builtin_amdgcn_cvt_pk_f32_fp8((int)u, false);
    f2v hi = __builtin_amdgcn_cvt_pk_f32_fp8((int)u, true);
    return make_float4(lo[0], lo[1], hi[0], hi[1]);
}

__device__ __forceinline__ void upd_add(float4& W, const float4 v)
{
    W.x += v.x; W.y += v.y; W.z += v.z; W.w += v.w;
}
__device__ __forceinline__ void upd_fma(float4& W, const float4 a, const float4 b)
{
    W.x = fmaf(a.x, b.x, W.x); W.y = fmaf(a.y, b.y, W.y);
    W.z = fmaf(a.z, b.z, W.z); W.w = fmaf(a.w, b.w, W.w);
}
__device__ __forceinline__ void upd_sub2(float4& W, const float4 e, const float4 l)
{
    W.x += e.x - l.x; W.y += e.y - l.y; W.z += e.z - l.z; W.w += e.w - l.w;
}
__device__ __forceinline__ void upd_fms(float4& W, const float4 ea, const float4 eb,
                                        const float4 la, const float4 lb)
{
    W.x = fmaf(ea.x, eb.x, fmaf(-la.x, lb.x, W.x));
    W.y = fmaf(ea.y, eb.y, fmaf(-la.y, lb.y, W.y));
    W.z = fmaf(ea.z, eb.z, fmaf(-la.z, lb.z, W.z));
    W.w = fmaf(ea.w, eb.w, fmaf(-la.w, lb.w, W.w));
}

// ---------------- P1: products + y-filter (R8-verbatim, measured ~46 us) ------------
#define GNONE 0
#define GLO   1
#define GHI   2

template<int MODE>
__device__ __forceinline__ void yfilt_run(int y0,
                                          const float* __restrict__ Ib,
                                          const float* __restrict__ Jb,
                                          u8* __restrict__ Fb)
{
    const float4 z4 = make_float4(0.f, 0.f, 0.f, 0.f);
    float4 W0 = z4, W1 = z4, W2 = z4, W3 = z4, W4 = z4;

    // init: window sum over raw rows [y0-10, y0+9]
#pragma unroll
    for (int k = 0; k < 20; ++k) {
        int u = y0 - 10 + k;
        float4 a, b;
        if (MODE == GLO) {                     // seg 0 only: u may be < 0
            a = (u >= 0) ? *(const float4*)(Ib + (size_t)u * Z_) : z4;
            b = (u >= 0) ? *(const float4*)(Jb + (size_t)u * Z_) : z4;
        } else {
            a = *(const float4*)(Ib + (size_t)u * Z_);
            b = *(const float4*)(Jb + (size_t)u * Z_);
        }
        upd_add(W0, a);
        upd_add(W1, b);
        upd_fma(W2, a, a);
        upd_fma(W3, b, b);
        upd_fma(W4, a, b);
    }

#pragma unroll
    for (int r = 0; r < YSEG1; ++r) {
        int y  = y0 + r;
        int ye = y + HALF;
        int yl = y - HALF - 1;
        float4 ea, eb, la, lb;
        if (MODE == GHI) {                     // seg 15 only: ye may be >= Y_
            ea = (ye < Y_) ? *(const float4*)(Ib + (size_t)ye * Z_) : z4;
            eb = (ye < Y_) ? *(const float4*)(Jb + (size_t)ye * Z_) : z4;
        } else {
            ea = *(const float4*)(Ib + (size_t)ye * Z_);
            eb = *(const float4*)(Jb + (size_t)ye * Z_);
        }
        if (MODE == GLO) {                     // seg 0 only: yl may be < 0
            la = (yl >= 0) ? *(const float4*)(Ib + (size_t)yl * Z_) : z4;
            lb = (yl >= 0) ? *(const float4*)(Jb + (size_t)yl * Z_) : z4;
        } else {
            la = *(const float4*)(Ib + (size_t)yl * Z_);
            lb = *(const float4*)(Jb + (size_t)yl * Z_);
        }
        upd_sub2(W0, ea, la);
        upd_sub2(W1, eb, lb);
        upd_fms(W2, ea, ea, la, la);
        upd_fms(W3, eb, eb, lb, lb);
        upd_fms(W4, ea, eb, la, lb);
        size_t o = (size_t)y * Z_;
        *(uint*)(Fb + o)            = pack4_fp8(W0.x, W0.y, W0.z, W0.w);
        *(uint*)(Fb + NTOT + o)     = pack4_fp8(W1.x, W1.y, W1.z, W1.w);
        *(uint*)(Fb + 2 * NTOT + o) = pack4_fp8(W2.x * 0.25f, W2.y * 0.25f,
                                                W2.z * 0.25f, W2.w * 0.25f);
        *(uint*)(Fb + 3 * NTOT + o) = pack4_fp8(W3.x * 0.25f, W3.y * 0.25f,
                                                W3.z * 0.25f, W3.w * 0.25f);
        *(uint*)(Fb + 4 * NTOT + o) = pack4_fp8(W4.x, W4.y, W4.z, W4.w);
    }
}

// thread = (seg, bx, z4). 800 blocks x 256 = 204800 = 40 z4 x 320 bx x 16 seg.
__global__ __launch_bounds__(256) void k_prod_yfilt(
    const float* __restrict__ I, const float* __restrict__ J,
    u8* __restrict__ Fy)
{
    int t   = blockIdx.x * 256 + threadIdx.x;
    int zg  = t % 40;
    int col = t / 40;
    int bx  = col % SXN;
    int seg = col / SXN;                       // [0, 16)
    const float* Ib = I + (size_t)bx * YZ + zg * 4;
    const float* Jb = J + (size_t)bx * YZ + zg * 4;
    u8* Fb = Fy + (size_t)bx * YZ + zg * 4;
    int y0 = seg * YSEG1;

    if (seg == 0)            yfilt_run<GLO>(y0, Ib, Jb, Fb);
    else if (seg == 15)      yfilt_run<GHI>(y0, Ib, Jb, Fb);
    else                     yfilt_run<GNONE>(y0, Ib, Jb, Fb);
}

// ---------------- P2: FUSED x-filter + z-filter + cc (latency-hidden) ---------------
__device__ __forceinline__ float cc_term(float w0, float w1, float w2, float w3,
                                         float w4, float inv_n)
{
    float cross = fmaf(-(w0 * w1), inv_n, w4);
    float Iv    = fmaf(-(w0 * w0), inv_n, w2 * 4.0f);   // unscale I2 (x0.25 in P1)
    float Jv    = fmaf(-(w1 * w1), inv_n, w3 * 4.0f);   // unscale J2
    float denom = fmaf(Iv, Jv, 1e-5f);
    return (cross * cross) * __builtin_amdgcn_rcpf(denom);
}

// z-window + cc for one (x-line, z8) unit from LDS
__device__ __forceinline__ float consume_unit(const uint* __restrict__ lds, int u,
                                              float inv_n)
{
    int xl = u / 20;
    int zg = u % 20;                           // z0 = 8*zg
    int ub = xl * 5 * LSTR + 4 + 2 * zg - 3;   // margins make all reads valid

    float s5[5][8];
#pragma unroll
    for (int c5 = 0; c5 < 5; ++c5) {
        int la = ub + c5 * LSTR;
        float f[32];                           // z span [z0-12, z0+19]
#pragma unroll
        for (int k = 0; k < 8; ++k) {
            float4 v = unpack4_fp8(lds[la + k]);
            f[4 * k + 0] = v.x; f[4 * k + 1] = v.y;
            f[4 * k + 2] = v.z; f[4 * k + 3] = v.w;
        }
        float s0 = 0.f;
#pragma unroll
        for (int i = 2; i <= 22; ++i) s0 += f[i];
        s5[c5][0] = s0;
#pragma unroll
        for (int r = 1; r < 8; ++r) { s0 += f[r + 22] - f[r + 1]; s5[c5][r] = s0; }
    }
    float a = 0.f;
#pragma unroll
    for (int r = 0; r < 8; ++r)
        a += cc_term(s5[0][r], s5[1][r], s5[2][r], s5[3][r], s5[4][r], inv_n);
    return a;
}

template<int SEG>
__device__ __forceinline__ void fused_body(const u8* __restrict__ Fy,
                                           double* __restrict__ part,
                                           int b, int y, int tid, int bid,
                                           uint* __restrict__ lds,
                                           float* __restrict__ wsum)
{
    constexpr int X0 = SEG * XSEG;
    const float inv_n = 1.0f / 9261.0f;

    // zero the z-margins of all 100 LDS lines (dwords 0..3 and 44..47).
    // Margins and produce-g0 interior are DISJOINT -> one shared barrier below.
#pragma unroll
    for (int it = 0; it < 4; ++it) {
        int i = tid + it * TPB_F;
        if (i < NLINES * 8) {
            int ln = i >> 3, m = i & 7;
            lds[ln * LSTR + (m < 4 ? m : 40 + m)] = 0u;
        }
    }

    // producers: 200 threads = (ch, z4), each with a private 21-deep x-ring
    const bool prod = (tid < 200);
    int c  = tid / 40;                         // [0,5)
    int z4 = tid % 40;
    const u8* base = Fy + (size_t)c * NTOT + (size_t)b * XYZ
                   + (size_t)y * Z_ + (size_t)z4 * 4;

    uint ring[WIN_];
    float4 W = make_float4(0.f, 0.f, 0.f, 0.f);
    if (prod) {
        // preload raw x-rows [X0-11, X0+9] (first step adds X0+10, drops X0-11)
#pragma unroll
        for (int k = 0; k < WIN_; ++k) {
            const int r = X0 - 11 + k;         // SEG>0: r >= 29, no guard
            uint v = 0u;
            if (SEG > 0 || r >= 0) v = *(const uint*)(base + (size_t)r * YZ);
            ring[k] = v;
            float4 t = unpack4_fp8(v);
            W.x += t.x; W.y += t.y; W.z += t.z; W.w += t.w;
        }
        // produce g0: steps 0..19 (loads inline, as R8)
#pragma unroll
        for (int s = 0; s < XGRP; ++s) {
            const int x  = X0 + s;             // compile-time
            const int ri = s % WIN_;
            uint e = *(const uint*)(base + (size_t)(x + HALF) * YZ);  // x+10 <= 149
            float4 te = unpack4_fp8(e);
            float4 tl = unpack4_fp8(ring[ri]);
            W.x += te.x - tl.x; W.y += te.y - tl.y;
            W.z += te.z - tl.z; W.w += te.w - tl.w;
            ring[ri] = e;
            lds[(s * 5 + c) * LSTR + 4 + z4] = pack4_fp8(W.x, W.y, W.z, W.w);
        }
    }
    __syncthreads();                           // margins + g0 interior ready

    // prefetch g1 enter rows into registers -- consume-g0's VALU hides latency
    uint e1[XGRP];
    if (prod) {
#pragma unroll
        for (int s = 0; s < XGRP; ++s) {
            const int x = X0 + XGRP + s;       // compile-time
            e1[s] = 0u;
            if (SEG < 3 || x + HALF < X_)
                e1[s] = *(const uint*)(base + (size_t)(x + HALF) * YZ);
        }
    }

    float lacc = 0.f;
    lacc += consume_unit(lds, tid, inv_n);     // consume g0
    if (tid < NUNITS - TPB_F)
        lacc += consume_unit(lds, tid + TPB_F, inv_n);
    __syncthreads();                           // g0 consumed; safe to overwrite

    if (prod) {
        // produce g1 from prefetched regs (pure VALU + LDS writes)
#pragma unroll
        for (int s = 0; s < XGRP; ++s) {
            const int ri = (XGRP + s) % WIN_;  // compile-time
            float4 te = unpack4_fp8(e1[s]);
            float4 tl = unpack4_fp8(ring[ri]);
            W.x += te.x - tl.x; W.y += te.y - tl.y;
            W.z += te.z - tl.z; W.w += te.w - tl.w;
            lds[(s * 5 + c) * LSTR + 4 + z4] = pack4_fp8(W.x, W.y, W.z, W.w);
        }
    }
    __syncthreads();                           // g1 interior ready
    lacc += consume_unit(lds, tid, inv_n);     // consume g1
    if (tid < NUNITS - TPB_F)
        lacc += consume_unit(lds, tid + TPB_F, inv_n);

#pragma unroll
    for (int off = 32; off > 0; off >>= 1) lacc += __shfl_down(lacc, off);
    if ((tid & 63) == 0) wsum[tid >> 6] = lacc;
    __syncthreads();
    if (tid == 0)
        part[bid] = (double)((wsum[0] + wsum[1]) + (wsum[2] + wsum[3]));
}

// 1536 blocks x 256: block = ((b,y) line, x-seg).
__global__ __launch_bounds__(TPB_F) void k_fused_xz(const u8* __restrict__ Fy,
                                                    double* __restrict__ part)
{
    __shared__ uint  lds[NLINES * LSTR];       // 19600 B
    __shared__ float wsum[TPB_F / 64];
    int tid  = threadIdx.x;
    int bid  = blockIdx.x;
    int seg  = bid / 384;
    int line = bid % 384;
    int b = line / Y_;
    int y = line % Y_;
    switch (seg) {
        case 0:  fused_body<0>(Fy, part, b, y, tid, bid, lds, wsum); break;
        case 1:  fused_body<1>(Fy, part, b, y, tid, bid, lds, wsum); break;
        case 2:  fused_body<2>(Fy, part, b, y, tid, bid, lds, wsum); break;
        default: fused_body<3>(Fy, part, b, y, tid, bid, lds, wsum); break;
    }
}

// ---------------- P4: sum 1536 partials + finalize ----------------
__global__ __launch_bounds__(256) void k_final4(const double* __restrict__ part,
                                                float* __restrict__ out)
{
    int tid = threadIdx.x;
    double s = 0.0;
#pragma unroll
    for (int k = 0; k < NBLK_F / 256; ++k)     // 6 each
        s += part[tid + 256 * k];
#pragma unroll
    for (int off = 32; off > 0; off >>= 1) s += __shfl_down(s, off);
    __shared__ double wsum[4];
    if ((tid & 63) == 0) wsum[tid >> 6] = s;
    __syncthreads();
    if (tid == 0) {
        double tot = (wsum[0] + wsum[1]) + (wsum[2] + wsum[3]);
        out[0] = 1.0f - (float)(tot / 9830400.0);
    }
}

extern "C" void kernel_launch(void* const* d_in, const int* in_sizes, int n_in,
                              void* d_out, int out_size, void* d_ws, size_t ws_size,
                              hipStream_t stream)
{
    const float* I = (const float*)d_in[0];
    const float* J = (const float*)d_in[1];
    float* out = (float*)d_out;

    char* ws = (char*)d_ws;
    double* part = (double*)ws;                // 1536 doubles
    u8* Fy = (u8*)(ws + 32768);                // 5 x 9.83 MB = 49.2 MB (fp8)

    k_prod_yfilt<<<dim3(800), 256, 0, stream>>>(I, J, Fy);
    k_fused_xz<<<dim3(NBLK_F), TPB_F, 0, stream>>>(Fy, part);
    k_final4<<<dim3(1), 256, 0, stream>>>(part, out);
}

// Round 14
// 153.438 us; speedup vs baseline: 1.0812x; 1.0134x over previous
//
#include <hip/hip_runtime.h>

// NCC loss (win=21) on vol [B=2, C=1, X=160, Y=192, Z=160] fp32.
// P1: products + y-filter -> Fy (fp8). R8-exact geometry (YSEG 12, 800x256):
//   measured ~46 us, pinned at bytes/~3.4 TB/s across 7 variants -- at floor.
// P2 k_fused_xz: x-filter + z-filter + cc fused (H never materialized).
//   R14: single-group blocks -- 8 x-segments of 20 (was 4 of 40), 3072 blocks.
//   Halves per-block serial depth (preload->produce->consume, ONE barrier
//   between produce and consume) and raises block supply 6 -> 8+/CU (LDS cap).
//   R13's prefetch/barrier-merge was null -> the stall is wave under-supply,
//   not the barrier drain. Ring preload doubles (L2/L3-hot Fy, cheap).
//   LSTR 49 (R12: odd stride kills the all-even-parity 4-way bank conflict).
// P4 sums 3072 partials. No atomics/fences (R3: ~31 ns/block serialization).
// fp8 e4m3 intermediates; I^2/J^2 carry x0.25 scale, cc_term unscales x4.

typedef unsigned char u8;
typedef float f2v __attribute__((ext_vector_type(2)));

#define B_   2
#define X_   160
#define Y_   192
#define Z_   160
#define WIN_ 21
#define HALF 10
#define YZ   (Y_ * Z_)                        // 30720
#define XYZ  (X_ * YZ)                        // 4915200
#define NTOT ((size_t)B_ * X_ * Y_ * Z_)      // 9830400 (elements == bytes in fp8)
#define SXN  (B_ * X_)                        // 320

#define YSEG1 12                              // P1: 16 y-segments of 12 (R4/R8 best)

// fused kernel geometry (R14: single-group)
#define XGRP   20                             // x-extent per block = one group
#define NSEGF  8                              // 8 x-segments
#define LSTR   49                             // LDS line stride (dwords, ODD): 4|40|4|1
#define NLINES (XGRP * 5)                     // 100 LDS lines
#define TPB_F  256
#define NBLK_F (384 * NSEGF)                  // 3072 = (B*Y) lines x 8 x-segs
#define NUNITS (XGRP * 20)                    // 400 consume units per block

__device__ __forceinline__ uint pack4_fp8(float a, float b, float c, float d)
{
    int u = 0;
    u = __builtin_amdgcn_cvt_pk_fp8_f32(a, b, u, false);
    u = __builtin_amdgcn_cvt_pk_fp8_f32(c, d, u, true);
    return (uint)u;
}

__device__ __forceinline__ float4 unpack4_fp8(uint u)
{
    f2v lo = __builtin_amdgcn_cvt_pk_f32_fp8((int)u, false);
    f2v hi = __builtin_amdgcn_cvt_pk_f32_fp8((int)u, true);
    return make_float4(lo[0], lo[1], hi[0], hi[1]);
}

__device__ __forceinline__ void upd_add(float4& W, const float4 v)
{
    W.x += v.x; W.y += v.y; W.z += v.z; W.w += v.w;
}
__device__ __forceinline__ void upd_fma(float4& W, const float4 a, const float4 b)
{
    W.x = fmaf(a.x, b.x, W.x); W.y = fmaf(a.y, b.y, W.y);
    W.z = fmaf(a.z, b.z, W.z); W.w = fmaf(a.w, b.w, W.w);
}
__device__ __forceinline__ void upd_sub2(float4& W, const float4 e, const float4 l)
{
    W.x += e.x - l.x; W.y += e.y - l.y; W.z += e.z - l.z; W.w += e.w - l.w;
}
__device__ __forceinline__ void upd_fms(float4& W, const float4 ea, const float4 eb,
                                        const float4 la, const float4 lb)
{
    W.x = fmaf(ea.x, eb.x, fmaf(-la.x, lb.x, W.x));
    W.y = fmaf(ea.y, eb.y, fmaf(-la.y, lb.y, W.y));
    W.z = fmaf(ea.z, eb.z, fmaf(-la.z, lb.z, W.z));
    W.w = fmaf(ea.w, eb.w, fmaf(-la.w, lb.w, W.w));
}

// ---------------- P1: products + y-filter (R8-verbatim, measured ~46 us) ------------
#define GNONE 0
#define GLO   1
#define GHI   2

template<int MODE>
__device__ __forceinline__ void yfilt_run(int y0,
                                          const float* __restrict__ Ib,
                                          const float* __restrict__ Jb,
                                          u8* __restrict__ Fb)
{
    const float4 z4 = make_float4(0.f, 0.f, 0.f, 0.f);
    float4 W0 = z4, W1 = z4, W2 = z4, W3 = z4, W4 = z4;

    // init: window sum over raw rows [y0-10, y0+9]
#pragma unroll
    for (int k = 0; k < 20; ++k) {
        int u = y0 - 10 + k;
        float4 a, b;
        if (MODE == GLO) {                     // seg 0 only: u may be < 0
            a = (u >= 0) ? *(const float4*)(Ib + (size_t)u * Z_) : z4;
            b = (u >= 0) ? *(const float4*)(Jb + (size_t)u * Z_) : z4;
        } else {
            a = *(const float4*)(Ib + (size_t)u * Z_);
            b = *(const float4*)(Jb + (size_t)u * Z_);
        }
        upd_add(W0, a);
        upd_add(W1, b);
        upd_fma(W2, a, a);
        upd_fma(W3, b, b);
        upd_fma(W4, a, b);
    }

#pragma unroll
    for (int r = 0; r < YSEG1; ++r) {
        int y  = y0 + r;
        int ye = y + HALF;
        int yl = y - HALF - 1;
        float4 ea, eb, la, lb;
        if (MODE == GHI) {                     // seg 15 only: ye may be >= Y_
            ea = (ye < Y_) ? *(const float4*)(Ib + (size_t)ye * Z_) : z4;
            eb = (ye < Y_) ? *(const float4*)(Jb + (size_t)ye * Z_) : z4;
        } else {
            ea = *(const float4*)(Ib + (size_t)ye * Z_);
            eb = *(const float4*)(Jb + (size_t)ye * Z_);
        }
        if (MODE == GLO) {                     // seg 0 only: yl may be < 0
            la = (yl >= 0) ? *(const float4*)(Ib + (size_t)yl * Z_) : z4;
            lb = (yl >= 0) ? *(const float4*)(Jb + (size_t)yl * Z_) : z4;
        } else {
            la = *(const float4*)(Ib + (size_t)yl * Z_);
            lb = *(const float4*)(Jb + (size_t)yl * Z_);
        }
        upd_sub2(W0, ea, la);
        upd_sub2(W1, eb, lb);
        upd_fms(W2, ea, ea, la, la);
        upd_fms(W3, eb, eb, lb, lb);
        upd_fms(W4, ea, eb, la, lb);
        size_t o = (size_t)y * Z_;
        *(uint*)(Fb + o)            = pack4_fp8(W0.x, W0.y, W0.z, W0.w);
        *(uint*)(Fb + NTOT + o)     = pack4_fp8(W1.x, W1.y, W1.z, W1.w);
        *(uint*)(Fb + 2 * NTOT + o) = pack4_fp8(W2.x * 0.25f, W2.y * 0.25f,
                                                W2.z * 0.25f, W2.w * 0.25f);
        *(uint*)(Fb + 3 * NTOT + o) = pack4_fp8(W3.x * 0.25f, W3.y * 0.25f,
                                                W3.z * 0.25f, W3.w * 0.25f);
        *(uint*)(Fb + 4 * NTOT + o) = pack4_fp8(W4.x, W4.y, W4.z, W4.w);
    }
}

// thread = (seg, bx, z4). 800 blocks x 256 = 204800 = 40 z4 x 320 bx x 16 seg.
__global__ __launch_bounds__(256) void k_prod_yfilt(
    const float* __restrict__ I, const float* __restrict__ J,
    u8* __restrict__ Fy)
{
    int t   = blockIdx.x * 256 + threadIdx.x;
    int zg  = t % 40;
    int col = t / 40;
    int bx  = col % SXN;
    int seg = col / SXN;                       // [0, 16)
    const float* Ib = I + (size_t)bx * YZ + zg * 4;
    const float* Jb = J + (size_t)bx * YZ + zg * 4;
    u8* Fb = Fy + (size_t)bx * YZ + zg * 4;
    int y0 = seg * YSEG1;

    if (seg == 0)            yfilt_run<GLO>(y0, Ib, Jb, Fb);
    else if (seg == 15)      yfilt_run<GHI>(y0, Ib, Jb, Fb);
    else                     yfilt_run<GNONE>(y0, Ib, Jb, Fb);
}

// ---------------- P2: FUSED x-filter + z-filter + cc (single-group blocks) ----------
__device__ __forceinline__ float cc_term(float w0, float w1, float w2, float w3,
                                         float w4, float inv_n)
{
    float cross = fmaf(-(w0 * w1), inv_n, w4);
    float Iv    = fmaf(-(w0 * w0), inv_n, w2 * 4.0f);   // unscale I2 (x0.25 in P1)
    float Jv    = fmaf(-(w1 * w1), inv_n, w3 * 4.0f);   // unscale J2
    float denom = fmaf(Iv, Jv, 1e-5f);
    return (cross * cross) * __builtin_amdgcn_rcpf(denom);
}

// z-window + cc for one (x-line, z8) unit from LDS
__device__ __forceinline__ float consume_unit(const uint* __restrict__ lds, int u,
                                              float inv_n)
{
    int xl = u / 20;
    int zg = u % 20;                           // z0 = 8*zg
    int ub = xl * 5 * LSTR + 4 + 2 * zg - 3;   // margins make all reads valid

    float s5[5][8];
#pragma unroll
    for (int c5 = 0; c5 < 5; ++c5) {
        int la = ub + c5 * LSTR;
        float f[32];                           // z span [z0-12, z0+19]
#pragma unroll
        for (int k = 0; k < 8; ++k) {
            float4 v = unpack4_fp8(lds[la + k]);
            f[4 * k + 0] = v.x; f[4 * k + 1] = v.y;
            f[4 * k + 2] = v.z; f[4 * k + 3] = v.w;
        }
        float s0 = 0.f;
#pragma unroll
        for (int i = 2; i <= 22; ++i) s0 += f[i];
        s5[c5][0] = s0;
#pragma unroll
        for (int r = 1; r < 8; ++r) { s0 += f[r + 22] - f[r + 1]; s5[c5][r] = s0; }
    }
    float a = 0.f;
#pragma unroll
    for (int r = 0; r < 8; ++r)
        a += cc_term(s5[0][r], s5[1][r], s5[2][r], s5[3][r], s5[4][r], inv_n);
    return a;
}

template<int SEG>
__device__ __forceinline__ void fused_body(const u8* __restrict__ Fy,
                                           double* __restrict__ part,
                                           int b, int y, int tid, int bid,
                                           uint* __restrict__ lds,
                                           float* __restrict__ wsum)
{
    constexpr int X0 = SEG * XGRP;
    const float inv_n = 1.0f / 9261.0f;

    // zero the z-margins of all 100 LDS lines (dwords 0..3 and 44..47).
    // Margins and produce interiors are DISJOINT -> share the single barrier.
#pragma unroll
    for (int it = 0; it < 4; ++it) {
        int i = tid + it * TPB_F;
        if (i < NLINES * 8) {
            int ln = i >> 3, m = i & 7;
            lds[ln * LSTR + (m < 4 ? m : 40 + m)] = 0u;
        }
    }

    // producers: 200 threads = (ch, z4), private 21-deep x-ring, ONE group
    const bool prod = (tid < 200);
    int c  = tid / 40;                         // [0,5)
    int z4 = tid % 40;
    const u8* base = Fy + (size_t)c * NTOT + (size_t)b * XYZ
                   + (size_t)y * Z_ + (size_t)z4 * 4;

    if (prod) {
        float4 W = make_float4(0.f, 0.f, 0.f, 0.f);
        uint ring[WIN_];
        // preload raw x-rows [X0-11, X0+9]
#pragma unroll
        for (int k = 0; k < WIN_; ++k) {
            const int r = X0 - 11 + k;         // SEG>0: r >= 9, no guard
            uint v = 0u;
            if (SEG > 0 || r >= 0) v = *(const uint*)(base + (size_t)r * YZ);
            ring[k] = v;
            float4 t = unpack4_fp8(v);
            W.x += t.x; W.y += t.y; W.z += t.z; W.w += t.w;
        }
        // produce: steps 0..19
#pragma unroll
        for (int s = 0; s < XGRP; ++s) {
            const int x = X0 + s;              // compile-time
            uint e = 0u;
            if (SEG < NSEGF - 1 || x + HALF < X_)      // guard only last seg
                e = *(const uint*)(base + (size_t)(x + HALF) * YZ);
            float4 te = unpack4_fp8(e);
            float4 tl = unpack4_fp8(ring[s]);  // leaving raw row x-11
            W.x += te.x - tl.x; W.y += te.y - tl.y;
            W.z += te.z - tl.z; W.w += te.w - tl.w;
            ring[s] = e;
            lds[(s * 5 + c) * LSTR + 4 + z4] = pack4_fp8(W.x, W.y, W.z, W.w);
        }
    }
    __syncthreads();                           // margins + interior ready

    float lacc = consume_unit(lds, tid, inv_n);
    if (tid < NUNITS - TPB_F)                  // units 256..399
        lacc += consume_unit(lds, tid + TPB_F, inv_n);

#pragma unroll
    for (int off = 32; off > 0; off >>= 1) lacc += __shfl_down(lacc, off);
    if ((tid & 63) == 0) wsum[tid >> 6] = lacc;
    __syncthreads();
    if (tid == 0)
        part[bid] = (double)((wsum[0] + wsum[1]) + (wsum[2] + wsum[3]));
}

// 3072 blocks x 256: block = ((b,y) line, x-seg of 20).
__global__ __launch_bounds__(TPB_F) void k_fused_xz(const u8* __restrict__ Fy,
                                                    double* __restrict__ part)
{
    __shared__ uint  lds[NLINES * LSTR];       // 19600 B
    __shared__ float wsum[TPB_F / 64];
    int tid  = threadIdx.x;
    int bid  = blockIdx.x;
    int seg  = bid / 384;                      // [0, 8)
    int line = bid % 384;
    int b = line / Y_;
    int y = line % Y_;
    switch (seg) {
        case 0:  fused_body<0>(Fy, part, b, y, tid, bid, lds, wsum); break;
        case 1:  fused_body<1>(Fy, part, b, y, tid, bid, lds, wsum); break;
        case 2:  fused_body<2>(Fy, part, b, y, tid, bid, lds, wsum); break;
        case 3:  fused_body<3>(Fy, part, b, y, tid, bid, lds, wsum); break;
        case 4:  fused_body<4>(Fy, part, b, y, tid, bid, lds, wsum); break;
        case 5:  fused_body<5>(Fy, part, b, y, tid, bid, lds, wsum); break;
        case 6:  fused_body<6>(Fy, part, b, y, tid, bid, lds, wsum); break;
        default: fused_body<7>(Fy, part, b, y, tid, bid, lds, wsum); break;
    }
}

// ---------------- P4: sum 3072 partials + finalize ----------------
__global__ __launch_bounds__(256) void k_final4(const double* __restrict__ part,
                                                float* __restrict__ out)
{
    int tid = threadIdx.x;
    double s = 0.0;
#pragma unroll
    for (int k = 0; k < NBLK_F / 256; ++k)     // 12 each
        s += part[tid + 256 * k];
#pragma unroll
    for (int off = 32; off > 0; off >>= 1) s += __shfl_down(s, off);
    __shared__ double wsum[4];
    if ((tid & 63) == 0) wsum[tid >> 6] = s;
    __syncthreads();
    if (tid == 0) {
        double tot = (wsum[0] + wsum[1]) + (wsum[2] + wsum[3]);
        out[0] = 1.0f - (float)(tot / 9830400.0);
    }
}

extern "C" void kernel_launch(void* const* d_in, const int* in_sizes, int n_in,
                              void* d_out, int out_size, void* d_ws, size_t ws_size,
                              hipStream_t stream)
{
    const float* I = (const float*)d_in[0];
    const float* J = (const float*)d_in[1];
    float* out = (float*)d_out;

    char* ws = (char*)d_ws;
    double* part = (double*)ws;                // 3072 doubles = 24.6 KB
    u8* Fy = (u8*)(ws + 32768);                // 5 x 9.83 MB = 49.2 MB (fp8)

    k_prod_yfilt<<<dim3(800), 256, 0, stream>>>(I, J, Fy);
    k_fused_xz<<<dim3(NBLK_F), TPB_F, 0, stream>>>(Fy, part);
    k_final4<<<dim3(1), 256, 0, stream>>>(part, out);
}